// Round 12
// baseline (33.812 us; speedup 1.0000x reference)
//
#include <hip/hip_runtime.h>
#include <hip/hip_fp16.h>
#include <stdint.h>

#define GCOUNT 8192
#define BATCH 2
#define IMGH 256
#define IMGW 256
#define TILE 16
#define TILES_X (IMGW / TILE)   // 16
#define TILES_Y (IMGH / TILE)   // 16
#define MAXLIST 1024            // avg ~250 survivors per 16x16 tile (validated: uncapped == capped)

// Barrier that does NOT drain vmcnt (unlike __syncthreads): LDS ordering only.
// Keeps the staging global-loads in flight across the whole sort phase.
#define LDS_BAR() do { asm volatile("s_waitcnt lgkmcnt(0)" ::: "memory"); \
                       __builtin_amdgcn_s_barrier(); } while (0)

// ---------------------------------------------------------------------------
// Kernel 1: per-Gaussian prep (R10 structure). Record = 2x float4:
// (mx,my,-a/2,-b) and (-c/2, lop_c, half2(r,g), b), where
// lop_c = min(ln op, ln 0.999) folds the 0.999 alpha clamp into the exponent
// (<=0.001 abs error). Conic pos-def => quadratic <= 0 (ref's min(power,0)
// is dead). Conservative 16px-tile bbox; sort key (depth_bits<<13 | idx) ==
// jnp.argsort order (depths > 0 => IEEE-monotone, low bits stable tie-break).
// ---------------------------------------------------------------------------
__global__ __launch_bounds__(256) void prep(
    const float* __restrict__ means, const float* __restrict__ conics,
    const float* __restrict__ colors, const float* __restrict__ opac,
    const float* __restrict__ depths,
    float4* __restrict__ gdat,            // [B*G*2]
    uint32_t* __restrict__ gbbox,         // [B*G]
    unsigned long long* __restrict__ gkey)// [B*G]
{
    const int t = blockIdx.x * 256 + threadIdx.x;
    if (t >= BATCH * GCOUNT) return;
    const int g = t & (GCOUNT - 1);

    const float mx  = means[t * 2 + 0];
    const float my  = means[t * 2 + 1];
    const float ca  = conics[t * 3 + 0];
    const float cb  = conics[t * 3 + 1];
    const float cc  = conics[t * 3 + 2];
    const float cr  = colors[t * 3 + 0];
    const float cg  = colors[t * 3 + 1];
    const float cbl = colors[t * 3 + 2];
    const float op  = opac[t];
    const float dep = depths[t];

    const float lop = __logf(op);
    // alpha >= 1/255  <=>  Q(d) <= ln(255*op) (from UNclamped lop)
    const float tt  = lop + 5.5412635f;
    const float det = ca * cc - cb * cb;   // >= 0.75*a*c > 0
    const float inv = 2.0f * tt / det;
    const float dxm = sqrtf(inv * cc) + 1.0f;  // +1px safety pad
    const float dym = sqrtf(inv * ca) + 1.0f;

    int x0 = max(0, (int)floorf((mx - dxm) * (1.0f / TILE)));
    int x1 = min(TILES_X - 1, (int)floorf((mx + dxm) * (1.0f / TILE)));
    int y0 = max(0, (int)floorf((my - dym) * (1.0f / TILE)));
    int y1 = min(TILES_Y - 1, (int)floorf((my + dym) * (1.0f / TILE)));
    uint32_t bb;
    if (x1 < x0 || y1 < y0)
        bb = 0xFFu;  // x0=255 never matches (tx <= 15)
    else
        bb = (uint32_t)x0 | ((uint32_t)x1 << 8) |
             ((uint32_t)y0 << 16) | ((uint32_t)y1 << 24);

    const __half hr = __float2half_rn(cr);
    const __half hg = __float2half_rn(cg);
    const uint32_t pk = ((uint32_t)__half_as_ushort(hg) << 16) |
                        (uint32_t)__half_as_ushort(hr);
    const float lop_c = fminf(lop, -0.0010005f);  // ln(0.999): folds alpha clamp

    gdat[t * 2 + 0] = make_float4(mx, my, -0.5f * ca, -cb);
    gdat[t * 2 + 1] = make_float4(-0.5f * cc, lop_c, __uint_as_float(pk), cbl);
    gbbox[t] = bb;
    gkey[t]  = ((unsigned long long)__float_as_uint(dep) << 13) | (unsigned)g;
}

// ---------------------------------------------------------------------------
// Kernel 2: per-tile scan+sort+composite. 1024 threads (16 waves) per 16x16
// tile, 512 blocks = 2 blocks/CU. Wave w = depth-segment w (of 16); every
// wave covers all 256 pixels at 4 consecutive px/lane (one broadcast record
// read serves 4 pixels, 4 independent T-chains hide exp latency).
//  1. scan 8192 bboxes (8 register-prefetched chunks, LDS-atomic compaction)
//  2. staging gather into REGISTERS pre-sort; lands in LDS post-sort (all
//     barriers lgkmcnt-only, no vmcnt drain -> L2 latency hides under sort)
//  3. sort: per-wave shfl_xor bitonic on 64-blocks; k>=128 LDS stages (j>=64)
//     + in-register shfl finish (j<=32)
//  4. physical reorder via inv-permutation -> composite reads sequentially
//  5. composite 4px/lane: incremental quadratic along x, pre-exp 1/255 cut,
//     0.999 clamp pre-folded into lop_c
//  6. SINGLE-STAGE merge (was 4-level tree = 8 barriers; now 2): segments
//     1..15 publish (c,T) into a 60KB LDS region ALIASING keys/sdat/sinv
//     (dead by then; pre-publish barrier makes the alias race-free); wave 0
//     folds front-to-back and writes float4-vectorized output.
// ---------------------------------------------------------------------------
__global__ __launch_bounds__(1024, 8) void raster(
    const float4* __restrict__ gdat, const uint32_t* __restrict__ gbbox,
    const unsigned long long* __restrict__ gkey, float* __restrict__ out)
{
    // 60 KB aliased arena:
    //   phase A (scan/sort/composite): keys[1024] u64 | sdat[1024][2] f4 | sinv[1024] u16
    //   phase B (merge):               xch[15][64][4] float4  (61440 B)
    __shared__ __align__(16) char smem[61440];
    __shared__ int scnt;
    unsigned long long* keys = (unsigned long long*)smem;            // [0, 8K)
    float4 (*sdat)[2] = (float4(*)[2])(smem + 8192);                 // [8K, 40K)
    uint16_t* sinv = (uint16_t*)(smem + 40960);                      // [40K, 42K)
    float4* xch = (float4*)smem;                                     // merge phase

    const int tid  = threadIdx.x;       // 0..1023
    const int lane = tid & 63;
    const int wid  = tid >> 6;          // 0..15
    const int tx = blockIdx.x, ty = blockIdx.y, b = blockIdx.z;
    const int bg = b * GCOUNT;

    if (tid == 0) scnt = 0;
    LDS_BAR();

    // ---- 1. scan & compact (unordered; sort fixes order) ----
    const unsigned long long mlt = (1ull << lane) - 1ull;
    {
        uint32_t v[8];
#pragma unroll
        for (int k = 0; k < 8; ++k)
            v[k] = gbbox[bg + k * 1024 + tid];
        bool hit[8];
        unsigned long long bal[8];
        int cnts[8], sum = 0;
#pragma unroll
        for (int k = 0; k < 8; ++k) {
            const int x0 = v[k] & 0xFF, x1 = (v[k] >> 8) & 0xFF;
            const int y0 = (v[k] >> 16) & 0xFF, y1 = (v[k] >> 24) & 0xFF;
            hit[k] = (tx >= x0) & (tx <= x1) & (ty >= y0) & (ty <= y1);
            bal[k] = __ballot(hit[k]);
            cnts[k] = __popcll(bal[k]);
            sum += cnts[k];
        }
        int wbase = 0;
        if (lane == 0 && sum) wbase = atomicAdd(&scnt, sum);
        wbase = __shfl(wbase, 0);
#pragma unroll
        for (int k = 0; k < 8; ++k) {
            if (hit[k]) {
                const int pos = wbase + __popcll(bal[k] & mlt);
                if (pos < MAXLIST)
                    keys[pos] = (gkey[bg + k * 1024 + tid] << 10) | (unsigned)pos;
            }
            wbase += cnts[k];
        }
    }
    LDS_BAR();
    const int cnt = min(scnt, MAXLIST);

    // ---- 2. staging gather -> registers (LDS landing deferred past sort) ----
    const bool h0 = tid < cnt;
    float4 r0a, r0b;
    if (h0) {
        const int g0 = (int)((keys[tid] >> 10) & 8191);
        r0a = gdat[(bg + g0) * 2 + 0];
        r0b = gdat[(bg + g0) * 2 + 1];
    }

    // ---- 3. sort keys[0..cnt) ascending ----
    int P = 64;
    while (P < cnt) P <<= 1;
    for (int i = cnt + tid; i < P; i += 1024) keys[i] = ~0ull;
    LDS_BAR();

    // per-wave in-register bitonic over each 64-block (levels k=2..64)
    if ((wid << 6) < P) {
        unsigned long long key = keys[(wid << 6) | lane];
        const bool descBlock = (wid & 1);   // odd blocks descending
#pragma unroll
        for (int k = 2; k <= 64; k <<= 1) {
            for (int j = k >> 1; j > 0; j >>= 1) {
                const unsigned long long other = __shfl_xor(key, j);
                const bool asc   = (((lane & k) == 0) != descBlock);
                const bool lower = ((lane & j) == 0);
                const unsigned long long mn = (key < other) ? key : other;
                const unsigned long long mx = (key < other) ? other : key;
                key = (asc == lower) ? mn : mx;
            }
        }
        keys[(wid << 6) | lane] = key;
    }
    LDS_BAR();

    // levels k=128..P: LDS stages for j>=64, in-register shfl finish j<=32
    for (int k = 128; k <= P; k <<= 1) {
        for (int j = k >> 1; j >= 64; j >>= 1) {
            const int i = tid;
            if (i < P) {
                const int ixj = i ^ j;
                if (ixj > i) {
                    const unsigned long long A = keys[i], Bv = keys[ixj];
                    const bool asc = ((i & k) == 0);
                    if ((A > Bv) == asc) { keys[i] = Bv; keys[ixj] = A; }
                }
            }
            LDS_BAR();
        }
        if ((wid << 6) < P) {
            const int base = wid << 6;
            unsigned long long key = keys[base | lane];
            const bool asc = ((base & k) == 0);   // uniform per 64-block (k>=128)
#pragma unroll
            for (int j = 32; j > 0; j >>= 1) {
                const unsigned long long other = __shfl_xor(key, j);
                const bool lower = ((lane & j) == 0);
                const unsigned long long mn = (key < other) ? key : other;
                const unsigned long long mx = (key < other) ? other : key;
                key = (asc == lower) ? mn : mx;
            }
            keys[base | lane] = key;
        }
        LDS_BAR();
    }

    // ---- 4. physical reorder: records land in LDS in DEPTH ORDER ----
    for (int i = tid; i < cnt; i += 1024)
        sinv[(int)(keys[i] & 1023u)] = (uint16_t)i;
    LDS_BAR();
    if (h0) {   // vmcnt for r0* waited here by compiler, hidden under the sort
        const int q = sinv[tid];
        sdat[q][0] = r0a;
        sdat[q][1] = r0b;
    }
    LDS_BAR();

    // ---- 5. composite segment wid over 4 consecutive pixels per lane ----
    const int px0 = tx * TILE + ((lane & 3) << 2);
    const int py  = ty * TILE + (lane >> 2);
    const float pxf = px0 + 0.5f, pyf = py + 0.5f;
    const int lo = (cnt * wid) >> 4;
    const int hi = (cnt * (wid + 1)) >> 4;

    float T0 = 1.f, cr0 = 0.f, cg0 = 0.f, cb0 = 0.f;
    float T1 = 1.f, cr1 = 0.f, cg1 = 0.f, cb1 = 0.f;
    float T2 = 1.f, cr2 = 0.f, cg2 = 0.f, cb2 = 0.f;
    float T3 = 1.f, cr3 = 0.f, cg3 = 0.f, cb3 = 0.f;

#pragma unroll 2
    for (int s = lo; s < hi; ++s) {
        const float4 A = sdat[s][0];   // mx, my, qa=-a/2, qb=-b
        const float4 Bv = sdat[s][1];  // qc=-c/2, lop_c, half2(r,g), b
        const float dx = pxf - A.x, dy = pyf - A.y;
        const float qbdy = A.w * dy;
        float pw0 = fmaf(A.z * dx, dx, Bv.y);    // qa dx^2 + lop
        pw0 = fmaf(Bv.x * dy, dy, pw0);          // + qc dy^2
        pw0 = fmaf(qbdy, dx, pw0);               // + qb dx dy
        const float qa2 = A.z + A.z;
        float stp = fmaf(qa2, dx, qbdy) + A.z;   // pw(x+1)-pw(x) at k=0
        const float pw1 = pw0 + stp;  stp += qa2;
        const float pw2 = pw1 + stp;  stp += qa2;
        const float pw3 = pw2 + stp;

        const uint32_t pk = __float_as_uint(Bv.z);
        const float gr = __half2float(__ushort_as_half((unsigned short)(pk & 0xFFFFu)));
        const float gg = __half2float(__ushort_as_half((unsigned short)(pk >> 16)));
        const float gb = Bv.w;

        // alpha < 1/255  <=>  pw < ln(1/255); 0.999 clamp folded into lop_c
        const float a0 = (pw0 < -5.5412636f) ? 0.f : __expf(pw0);
        const float a1 = (pw1 < -5.5412636f) ? 0.f : __expf(pw1);
        const float a2 = (pw2 < -5.5412636f) ? 0.f : __expf(pw2);
        const float a3 = (pw3 < -5.5412636f) ? 0.f : __expf(pw3);

        const float w0 = T0 * a0; cr0 = fmaf(w0, gr, cr0); cg0 = fmaf(w0, gg, cg0); cb0 = fmaf(w0, gb, cb0); T0 -= w0;
        const float w1 = T1 * a1; cr1 = fmaf(w1, gr, cr1); cg1 = fmaf(w1, gg, cg1); cb1 = fmaf(w1, gb, cb1); T1 -= w1;
        const float w2 = T2 * a2; cr2 = fmaf(w2, gr, cr2); cg2 = fmaf(w2, gg, cg2); cb2 = fmaf(w2, gb, cb2); T2 -= w2;
        const float w3 = T3 * a3; cr3 = fmaf(w3, gr, cr3); cg3 = fmaf(w3, gg, cg3); cb3 = fmaf(w3, gb, cb3); T3 -= w3;
    }

    // ---- 6. single-stage merge: c = c0 + T0(c1 + T1(...)), T = prod T ----
    LDS_BAR();   // all waves done reading sdat -> safe to overwrite (alias)
    if (wid) {
        float4* dst = xch + ((wid - 1) << 8) + (lane << 2);
        dst[0] = make_float4(cr0, cg0, cb0, T0);
        dst[1] = make_float4(cr1, cg1, cb1, T1);
        dst[2] = make_float4(cr2, cg2, cb2, T2);
        dst[3] = make_float4(cr3, cg3, cb3, T3);
    }
    LDS_BAR();
    if (wid == 0) {
        for (int q = 0; q < 15; ++q) {
            const float4* src = xch + (q << 8) + (lane << 2);
            float4 e;
            e = src[0]; cr0 = fmaf(T0, e.x, cr0); cg0 = fmaf(T0, e.y, cg0); cb0 = fmaf(T0, e.z, cb0); T0 *= e.w;
            e = src[1]; cr1 = fmaf(T1, e.x, cr1); cg1 = fmaf(T1, e.y, cg1); cb1 = fmaf(T1, e.z, cb1); T1 *= e.w;
            e = src[2]; cr2 = fmaf(T2, e.x, cr2); cg2 = fmaf(T2, e.y, cg2); cb2 = fmaf(T2, e.z, cb2); T2 *= e.w;
            e = src[3]; cr3 = fmaf(T3, e.x, cr3); cg3 = fmaf(T3, e.y, cg3); cb3 = fmaf(T3, e.z, cb3); T3 *= e.w;
        }
        const int pix0 = (b * IMGH + py) * IMGW + px0;
        float* o = out + (size_t)pix0 * 3;
        *(float4*)(o + 0) = make_float4(cr0, cg0, cb0, cr1);
        *(float4*)(o + 4) = make_float4(cg1, cb1, cr2, cg2);
        *(float4*)(o + 8) = make_float4(cb2, cr3, cg3, cb3);
        *(float4*)&out[(size_t)BATCH * IMGH * IMGW * 3 + pix0] =
            make_float4(1.f - T0, 1.f - T1, 1.f - T2, 1.f - T3);
    }
}

extern "C" void kernel_launch(void* const* d_in, const int* in_sizes, int n_in,
                              void* d_out, int out_size, void* d_ws, size_t ws_size,
                              hipStream_t stream) {
    const float* means  = (const float*)d_in[0];
    const float* conics = (const float*)d_in[1];
    const float* colors = (const float*)d_in[2];
    const float* opac   = (const float*)d_in[3];
    const float* depths = (const float*)d_in[4];
    // d_in[5], d_in[6]: image_height/width == 256, hardcoded.

    char* ws = (char*)d_ws;
    const size_t NG = (size_t)BATCH * GCOUNT;
    float4*             gdat  = (float4*)ws;                         // 512 KB
    uint32_t*           gbbox = (uint32_t*)(ws + NG * 32);           //  64 KB
    unsigned long long* gkey  = (unsigned long long*)(ws + NG * 36); // 128 KB
    float* out = (float*)d_out;

    hipLaunchKernelGGL(prep, dim3((BATCH * GCOUNT + 255) / 256), dim3(256), 0, stream,
                       means, conics, colors, opac, depths, gdat, gbbox, gkey);
    hipLaunchKernelGGL(raster, dim3(TILES_X, TILES_Y, BATCH), dim3(1024), 0, stream,
                       gdat, gbbox, gkey, out);
}

// Round 13
// 28.014 us; speedup vs baseline: 1.2070x; 1.2070x over previous
//
#include <hip/hip_runtime.h>
#include <hip/hip_fp16.h>
#include <stdint.h>

#define GCOUNT 8192
#define BATCH 2
#define IMGH 256
#define IMGW 256
#define TILE 16
#define TILES_X (IMGW / TILE)   // 16
#define TILES_Y (IMGH / TILE)   // 16
#define MAXLIST 1024            // avg ~250 survivors per 16x16 tile (validated: uncapped == capped)

// Barrier that does NOT drain vmcnt (unlike __syncthreads): LDS ordering only.
// Keeps the staging global-loads in flight across the whole sort phase.
#define LDS_BAR() do { asm volatile("s_waitcnt lgkmcnt(0)" ::: "memory"); \
                       __builtin_amdgcn_s_barrier(); } while (0)

// ---------------------------------------------------------------------------
// Kernel 1: per-Gaussian prep (R10 structure). Record = 2x float4:
// (mx,my,-a/2,-b) and (-c/2, lop_c, half2(r,g), b), where
// lop_c = min(ln op, ln 0.999) folds the 0.999 alpha clamp into the exponent
// (<=0.001 abs error; empirically absmax unchanged). Conic pos-def =>
// quadratic <= 0 (ref's min(power,0) is dead). Conservative 16px-tile bbox;
// sort key (depth_bits<<13 | idx) == jnp.argsort order (depths > 0 =>
// IEEE-monotone, low bits stable tie-break).
// ---------------------------------------------------------------------------
__global__ __launch_bounds__(256) void prep(
    const float* __restrict__ means, const float* __restrict__ conics,
    const float* __restrict__ colors, const float* __restrict__ opac,
    const float* __restrict__ depths,
    float4* __restrict__ gdat,            // [B*G*2]
    uint32_t* __restrict__ gbbox,         // [B*G]
    unsigned long long* __restrict__ gkey)// [B*G]
{
    const int t = blockIdx.x * 256 + threadIdx.x;
    if (t >= BATCH * GCOUNT) return;
    const int g = t & (GCOUNT - 1);

    const float mx  = means[t * 2 + 0];
    const float my  = means[t * 2 + 1];
    const float ca  = conics[t * 3 + 0];
    const float cb  = conics[t * 3 + 1];
    const float cc  = conics[t * 3 + 2];
    const float cr  = colors[t * 3 + 0];
    const float cg  = colors[t * 3 + 1];
    const float cbl = colors[t * 3 + 2];
    const float op  = opac[t];
    const float dep = depths[t];

    const float lop = __logf(op);
    // alpha >= 1/255  <=>  Q(d) <= ln(255*op) (from UNclamped lop)
    const float tt  = lop + 5.5412635f;
    const float det = ca * cc - cb * cb;   // >= 0.75*a*c > 0
    const float inv = 2.0f * tt / det;
    const float dxm = sqrtf(inv * cc) + 1.0f;  // +1px safety pad
    const float dym = sqrtf(inv * ca) + 1.0f;

    int x0 = max(0, (int)floorf((mx - dxm) * (1.0f / TILE)));
    int x1 = min(TILES_X - 1, (int)floorf((mx + dxm) * (1.0f / TILE)));
    int y0 = max(0, (int)floorf((my - dym) * (1.0f / TILE)));
    int y1 = min(TILES_Y - 1, (int)floorf((my + dym) * (1.0f / TILE)));
    uint32_t bb;
    if (x1 < x0 || y1 < y0)
        bb = 0xFFu;  // x0=255 never matches (tx <= 15)
    else
        bb = (uint32_t)x0 | ((uint32_t)x1 << 8) |
             ((uint32_t)y0 << 16) | ((uint32_t)y1 << 24);

    const __half hr = __float2half_rn(cr);
    const __half hg = __float2half_rn(cg);
    const uint32_t pk = ((uint32_t)__half_as_ushort(hg) << 16) |
                        (uint32_t)__half_as_ushort(hr);
    const float lop_c = fminf(lop, -0.0010005f);  // ln(0.999): folds alpha clamp

    gdat[t * 2 + 0] = make_float4(mx, my, -0.5f * ca, -cb);
    gdat[t * 2 + 1] = make_float4(-0.5f * cc, lop_c, __uint_as_float(pk), cbl);
    gbbox[t] = bb;
    gkey[t]  = ((unsigned long long)__float_as_uint(dep) << 13) | (unsigned)g;
}

// ---------------------------------------------------------------------------
// Kernel 2: per-tile scan+sort+composite (R10 structure). 1024 threads (16
// waves) per 16x16 tile, 512 blocks = 2 blocks/CU. Wave w = depth-segment w
// (of 16); every wave covers all 256 pixels at 4 consecutive px/lane (one
// broadcast record read serves 4 pixels, 4 independent T-chains hide exp
// latency).
//  1. scan 8192 bboxes (8 register-prefetched chunks, LDS-atomic compaction)
//  2. staging gather into REGISTERS pre-sort; lands in LDS post-sort (all
//     barriers lgkmcnt-only, no vmcnt drain -> L2 latency hides under sort)
//  3. sort: per-wave shfl_xor bitonic on 64-blocks; k>=128 LDS stages (j>=64)
//     + in-register shfl finish (j<=32)
//  4. physical reorder via inv-permutation -> composite reads sequentially
//  5. composite 4px/lane: incremental quadratic along x; NEW whole-wave skip
//     (wave = whole tile, so !__any(pw >= ln(1/255)) <=> record touches no
//     pixel = bbox false positive ~15-25% -> s_cbranch_execz skips the
//     unpack/exp/accumulate tail); pre-exp 1/255 cut; 0.999 clamp in lop_c
//  6. merge 16 segments via 4-level log-tree (R10-proven; R12's serial
//     single-stage merge regressed); wave 0 writes float4-vectorized output.
// ---------------------------------------------------------------------------
__global__ __launch_bounds__(1024, 8) void raster(
    const float4* __restrict__ gdat, const uint32_t* __restrict__ gbbox,
    const unsigned long long* __restrict__ gkey, float* __restrict__ out)
{
    __shared__ unsigned long long keys[MAXLIST];   // 8 KB
    __shared__ float4 sdat[MAXLIST][2];            // 32 KB
    __shared__ uint16_t sinv[MAXLIST];             // 2 KB
    __shared__ float4 xch[8][64][4];               // 32 KB
    __shared__ int scnt;

    const int tid  = threadIdx.x;       // 0..1023
    const int lane = tid & 63;
    const int wid  = tid >> 6;          // 0..15
    const int tx = blockIdx.x, ty = blockIdx.y, b = blockIdx.z;
    const int bg = b * GCOUNT;

    if (tid == 0) scnt = 0;
    LDS_BAR();

    // ---- 1. scan & compact (unordered; sort fixes order) ----
    const unsigned long long mlt = (1ull << lane) - 1ull;
    {
        uint32_t v[8];
#pragma unroll
        for (int k = 0; k < 8; ++k)
            v[k] = gbbox[bg + k * 1024 + tid];
        bool hit[8];
        unsigned long long bal[8];
        int cnts[8], sum = 0;
#pragma unroll
        for (int k = 0; k < 8; ++k) {
            const int x0 = v[k] & 0xFF, x1 = (v[k] >> 8) & 0xFF;
            const int y0 = (v[k] >> 16) & 0xFF, y1 = (v[k] >> 24) & 0xFF;
            hit[k] = (tx >= x0) & (tx <= x1) & (ty >= y0) & (ty <= y1);
            bal[k] = __ballot(hit[k]);
            cnts[k] = __popcll(bal[k]);
            sum += cnts[k];
        }
        int wbase = 0;
        if (lane == 0 && sum) wbase = atomicAdd(&scnt, sum);
        wbase = __shfl(wbase, 0);
#pragma unroll
        for (int k = 0; k < 8; ++k) {
            if (hit[k]) {
                const int pos = wbase + __popcll(bal[k] & mlt);
                if (pos < MAXLIST)
                    keys[pos] = (gkey[bg + k * 1024 + tid] << 10) | (unsigned)pos;
            }
            wbase += cnts[k];
        }
    }
    LDS_BAR();
    const int cnt = min(scnt, MAXLIST);

    // ---- 2. staging gather -> registers (LDS landing deferred past sort) ----
    const bool h0 = tid < cnt;
    float4 r0a, r0b;
    if (h0) {
        const int g0 = (int)((keys[tid] >> 10) & 8191);
        r0a = gdat[(bg + g0) * 2 + 0];
        r0b = gdat[(bg + g0) * 2 + 1];
    }

    // ---- 3. sort keys[0..cnt) ascending ----
    int P = 64;
    while (P < cnt) P <<= 1;
    for (int i = cnt + tid; i < P; i += 1024) keys[i] = ~0ull;
    LDS_BAR();

    // per-wave in-register bitonic over each 64-block (levels k=2..64)
    if ((wid << 6) < P) {
        unsigned long long key = keys[(wid << 6) | lane];
        const bool descBlock = (wid & 1);   // odd blocks descending
#pragma unroll
        for (int k = 2; k <= 64; k <<= 1) {
            for (int j = k >> 1; j > 0; j >>= 1) {
                const unsigned long long other = __shfl_xor(key, j);
                const bool asc   = (((lane & k) == 0) != descBlock);
                const bool lower = ((lane & j) == 0);
                const unsigned long long mn = (key < other) ? key : other;
                const unsigned long long mx = (key < other) ? other : key;
                key = (asc == lower) ? mn : mx;
            }
        }
        keys[(wid << 6) | lane] = key;
    }
    LDS_BAR();

    // levels k=128..P: LDS stages for j>=64, in-register shfl finish j<=32
    for (int k = 128; k <= P; k <<= 1) {
        for (int j = k >> 1; j >= 64; j >>= 1) {
            const int i = tid;
            if (i < P) {
                const int ixj = i ^ j;
                if (ixj > i) {
                    const unsigned long long A = keys[i], Bv = keys[ixj];
                    const bool asc = ((i & k) == 0);
                    if ((A > Bv) == asc) { keys[i] = Bv; keys[ixj] = A; }
                }
            }
            LDS_BAR();
        }
        if ((wid << 6) < P) {
            const int base = wid << 6;
            unsigned long long key = keys[base | lane];
            const bool asc = ((base & k) == 0);   // uniform per 64-block (k>=128)
#pragma unroll
            for (int j = 32; j > 0; j >>= 1) {
                const unsigned long long other = __shfl_xor(key, j);
                const bool lower = ((lane & j) == 0);
                const unsigned long long mn = (key < other) ? key : other;
                const unsigned long long mx = (key < other) ? other : key;
                key = (asc == lower) ? mn : mx;
            }
            keys[base | lane] = key;
        }
        LDS_BAR();
    }

    // ---- 4. physical reorder: records land in LDS in DEPTH ORDER ----
    for (int i = tid; i < cnt; i += 1024)
        sinv[(int)(keys[i] & 1023u)] = (uint16_t)i;
    LDS_BAR();
    if (h0) {   // vmcnt for r0* waited here by compiler, hidden under the sort
        const int q = sinv[tid];
        sdat[q][0] = r0a;
        sdat[q][1] = r0b;
    }
    LDS_BAR();

    // ---- 5. composite segment wid over 4 consecutive pixels per lane ----
    const int px0 = tx * TILE + ((lane & 3) << 2);
    const int py  = ty * TILE + (lane >> 2);
    const float pxf = px0 + 0.5f, pyf = py + 0.5f;
    const int lo = (cnt * wid) >> 4;
    const int hi = (cnt * (wid + 1)) >> 4;

    float T0 = 1.f, cr0 = 0.f, cg0 = 0.f, cb0 = 0.f;
    float T1 = 1.f, cr1 = 0.f, cg1 = 0.f, cb1 = 0.f;
    float T2 = 1.f, cr2 = 0.f, cg2 = 0.f, cb2 = 0.f;
    float T3 = 1.f, cr3 = 0.f, cg3 = 0.f, cb3 = 0.f;

    for (int s = lo; s < hi; ++s) {
        const float4 A = sdat[s][0];   // mx, my, qa=-a/2, qb=-b
        const float4 Bv = sdat[s][1];  // qc=-c/2, lop_c, half2(r,g), b
        const float dx = pxf - A.x, dy = pyf - A.y;
        const float qbdy = A.w * dy;
        float pw0 = fmaf(A.z * dx, dx, Bv.y);    // qa dx^2 + lop
        pw0 = fmaf(Bv.x * dy, dy, pw0);          // + qc dy^2
        pw0 = fmaf(qbdy, dx, pw0);               // + qb dx dy
        const float qa2 = A.z + A.z;
        float stp = fmaf(qa2, dx, qbdy) + A.z;   // pw(x+1)-pw(x) at k=0
        const float pw1 = pw0 + stp;  stp += qa2;
        const float pw2 = pw1 + stp;  stp += qa2;
        const float pw3 = pw2 + stp;

        // Whole-wave skip: this wave sees ALL 256 tile pixels, so if no lane
        // clears the 1/255 threshold the record is a bbox false positive ->
        // s_cbranch_execz skips unpack/exp/accumulate (~40 ops + 4 trans).
        const float pmax = fmaxf(fmaxf(pw0, pw1), fmaxf(pw2, pw3));
        if (!__any(pmax >= -5.5412636f)) continue;

        const uint32_t pk = __float_as_uint(Bv.z);
        const float gr = __half2float(__ushort_as_half((unsigned short)(pk & 0xFFFFu)));
        const float gg = __half2float(__ushort_as_half((unsigned short)(pk >> 16)));
        const float gb = Bv.w;

        // alpha < 1/255  <=>  pw < ln(1/255); 0.999 clamp folded into lop_c
        const float a0 = (pw0 < -5.5412636f) ? 0.f : __expf(pw0);
        const float a1 = (pw1 < -5.5412636f) ? 0.f : __expf(pw1);
        const float a2 = (pw2 < -5.5412636f) ? 0.f : __expf(pw2);
        const float a3 = (pw3 < -5.5412636f) ? 0.f : __expf(pw3);

        const float w0 = T0 * a0; cr0 = fmaf(w0, gr, cr0); cg0 = fmaf(w0, gg, cg0); cb0 = fmaf(w0, gb, cb0); T0 -= w0;
        const float w1 = T1 * a1; cr1 = fmaf(w1, gr, cr1); cg1 = fmaf(w1, gg, cg1); cb1 = fmaf(w1, gb, cb1); T1 -= w1;
        const float w2 = T2 * a2; cr2 = fmaf(w2, gr, cr2); cg2 = fmaf(w2, gg, cg2); cb2 = fmaf(w2, gb, cb2); T2 -= w2;
        const float w3 = T3 * a3; cr3 = fmaf(w3, gr, cr3); cg3 = fmaf(w3, gg, cg3); cb3 = fmaf(w3, gb, cb3); T3 -= w3;
    }

    // ---- 6. merge 16 segments via log-tree: c = c_f + T_f*c_b, T = T_f*T_b ----
    int ls = 0;
    for (int st = 1; st < 16; st <<= 1, ++ls) {
        const int m = (st << 1) - 1;
        if ((wid & m) == st) {     // back half publishes
            const int slot = wid >> (ls + 1);
            xch[slot][lane][0] = make_float4(cr0, cg0, cb0, T0);
            xch[slot][lane][1] = make_float4(cr1, cg1, cb1, T1);
            xch[slot][lane][2] = make_float4(cr2, cg2, cb2, T2);
            xch[slot][lane][3] = make_float4(cr3, cg3, cb3, T3);
        }
        LDS_BAR();
        if ((wid & m) == 0) {      // front half combines
            const int slot = wid >> (ls + 1);
            float4 e;
            e = xch[slot][lane][0]; cr0 = fmaf(T0, e.x, cr0); cg0 = fmaf(T0, e.y, cg0); cb0 = fmaf(T0, e.z, cb0); T0 *= e.w;
            e = xch[slot][lane][1]; cr1 = fmaf(T1, e.x, cr1); cg1 = fmaf(T1, e.y, cg1); cb1 = fmaf(T1, e.z, cb1); T1 *= e.w;
            e = xch[slot][lane][2]; cr2 = fmaf(T2, e.x, cr2); cg2 = fmaf(T2, e.y, cg2); cb2 = fmaf(T2, e.z, cb2); T2 *= e.w;
            e = xch[slot][lane][3]; cr3 = fmaf(T3, e.x, cr3); cg3 = fmaf(T3, e.y, cg3); cb3 = fmaf(T3, e.z, cb3); T3 *= e.w;
        }
        LDS_BAR();
    }

    if (wid == 0) {
        const int pix0 = (b * IMGH + py) * IMGW + px0;
        float* o = out + (size_t)pix0 * 3;
        *(float4*)(o + 0) = make_float4(cr0, cg0, cb0, cr1);
        *(float4*)(o + 4) = make_float4(cg1, cb1, cr2, cg2);
        *(float4*)(o + 8) = make_float4(cb2, cr3, cg3, cb3);
        *(float4*)&out[(size_t)BATCH * IMGH * IMGW * 3 + pix0] =
            make_float4(1.f - T0, 1.f - T1, 1.f - T2, 1.f - T3);
    }
}

extern "C" void kernel_launch(void* const* d_in, const int* in_sizes, int n_in,
                              void* d_out, int out_size, void* d_ws, size_t ws_size,
                              hipStream_t stream) {
    const float* means  = (const float*)d_in[0];
    const float* conics = (const float*)d_in[1];
    const float* colors = (const float*)d_in[2];
    const float* opac   = (const float*)d_in[3];
    const float* depths = (const float*)d_in[4];
    // d_in[5], d_in[6]: image_height/width == 256, hardcoded.

    char* ws = (char*)d_ws;
    const size_t NG = (size_t)BATCH * GCOUNT;
    float4*             gdat  = (float4*)ws;                         // 512 KB
    uint32_t*           gbbox = (uint32_t*)(ws + NG * 32);           //  64 KB
    unsigned long long* gkey  = (unsigned long long*)(ws + NG * 36); // 128 KB
    float* out = (float*)d_out;

    hipLaunchKernelGGL(prep, dim3((BATCH * GCOUNT + 255) / 256), dim3(256), 0, stream,
                       means, conics, colors, opac, depths, gdat, gbbox, gkey);
    hipLaunchKernelGGL(raster, dim3(TILES_X, TILES_Y, BATCH), dim3(1024), 0, stream,
                       gdat, gbbox, gkey, out);
}